// Round 17
// baseline (88.047 us; speedup 1.0000x reference)
//
#include <hip/hip_runtime.h>
#include <hip/hip_bf16.h>
#include <stdint.h>

#define BATCH 8192
#define DIM   1024
#define BM 128
#define BN 64
#define BK 64
#define BUF 24576                // A 16K + B 8K per stage buffer

typedef __attribute__((ext_vector_type(4))) float f32x4;
typedef __attribute__((ext_vector_type(8))) short bf16x8;
typedef __attribute__((ext_vector_type(8))) unsigned short u16x8;

#define AS1(p) ((const __attribute__((address_space(1))) void*)(p))
#define AS3(p) ((__attribute__((address_space(3))) void*)(p))

__device__ __forceinline__ unsigned short f2bf(float f) {
    union { __hip_bfloat16 h; unsigned short u; } v;
    v.h = __hip_bfloat16(f);
    return v.u;
}
__device__ __forceinline__ float sigma_f(float x) {
    float x2 = x * x;
    return x2 * __builtin_amdgcn_rcpf(1.0f + x2);
}

// ---------------------------------------------------------------------------
// K1: sigma(x) -> bf16 ws + out2 zeros (4096 blocks) | A -> bf16 (512 blocks)
// ---------------------------------------------------------------------------
__global__ __launch_bounds__(256) void prep_kernel(
    const float* __restrict__ x, const float* __restrict__ A,
    unsigned short* __restrict__ sigb, unsigned short* __restrict__ Abf,
    float* __restrict__ out2)
{
    const int i = blockIdx.x * 256 + threadIdx.x;
    if (i < BATCH * DIM / 8) {
        f32x4 v0 = ((const f32x4*)x)[i * 2];
        f32x4 v1 = ((const f32x4*)x)[i * 2 + 1];
        u16x8 sb;
#pragma unroll
        for (int e = 0; e < 4; ++e) {
            sb[e]     = f2bf(sigma_f(v0[e]));
            sb[e + 4] = f2bf(sigma_f(v1[e]));
        }
        ((u16x8*)sigb)[i] = sb;
        ((f32x4*)out2)[i * 2]     = f32x4{0.f, 0.f, 0.f, 0.f};
        ((f32x4*)out2)[i * 2 + 1] = f32x4{0.f, 0.f, 0.f, 0.f};
    } else {
        const int j = i - BATCH * DIM / 8;       // < 131072
        f32x4 v0 = ((const f32x4*)A)[j * 2];
        f32x4 v1 = ((const f32x4*)A)[j * 2 + 1];
        u16x8 ab;
#pragma unroll
        for (int e = 0; e < 4; ++e) {
            ab[e]     = f2bf(v0[e]);
            ab[e + 4] = f2bf(v1[e]);
        }
        ((u16x8*)Abf)[j] = ab;
    }
}

// ---------------------------------------------------------------------------
// K2: persistent 2-tile GEMM with swapped-operand MFMA.
//   512 blocks (2/CU, ONE round), 512 thr (8 waves, 4x2 grid, 32x32/wave).
//   Each block: tiles (bm,bn0) and (bm,bn0+8), continuous 32-step K-loop,
//   3-buffer glds staging, counted vmcnt, raw barriers (R13-proven).
//   acc = mfma(bfr, af): C-frag transposed -> each thread holds f32x4 of
//   4 CONSECUTIVE COLS -> direct v4 epilogue, NO LDS C-dump.
//   T0 epilogue reads issued at step 8, math+stores at step 16 (hidden
//   under T1's K-loop); T1 reads at step 24, epilogue after step 31.
//   vmcnt per step: 15@{9,10}, 11@{17,18}, 17@{25,26}, 0@31, else 3.
// ---------------------------------------------------------------------------
__global__ __launch_bounds__(512, 4) void gemm_kernel(
    const float* __restrict__ x, const float* __restrict__ ex,
    const float* __restrict__ W, const float* __restrict__ tgt,
    const unsigned short* __restrict__ sigb,
    const unsigned short* __restrict__ Abf,
    float* __restrict__ out0, float* __restrict__ out1)
{
    __shared__ __align__(16) char lds[3 * BUF];

    // ---- block mapping: same-bm blocks share an XCD
    const int b     = blockIdx.x;
    const int xcd   = b & 7;
    const int local = b >> 3;                    // 0..63
    const int bm    = xcd * 8 + (local >> 3);    // 0..63
    const int bn0   = local & 7;                 // 0..7
    const int bn1   = bn0 + 8;

    const int tid  = threadIdx.x;
    const int lane = tid & 63;
    const int wid  = tid >> 6;                   // 0..7
    const int wr   = wid >> 1, wc = wid & 1;     // 4x2 wave grid
    const int l15  = lane & 15;
    const int l4   = lane >> 4;                  // 0..3

    // ---- staging sources (pre-swizzled source, linear LDS dest)
    const int swz = (((lane & 7) ^ (lane >> 3)) << 4);
    const char* gS = (const char*)sigb +
        ((size_t)(bm * BM + wid * 8 + (lane >> 3)) * DIM) * 2 + swz;
    const char* gB0 = (const char*)Abf +
        ((size_t)(bn0 * BN + wid * 8 + (lane >> 3)) * DIM) * 2 + swz;
    const char* gB1 = (const char*)Abf +
        ((size_t)(bn1 * BN + wid * 8 + (lane >> 3)) * DIM) * 2 + swz;

    // ---- fragment read constants
    const int rd_sw = (lane & 7) << 4;
    const int cb0   = l4 << 4;

    f32x4 acc0[2][2], acc1[2][2];
#pragma unroll
    for (int mi = 0; mi < 2; ++mi)
#pragma unroll
        for (int ni = 0; ni < 2; ++ni) {
            acc0[mi][ni] = f32x4{0.f, 0.f, 0.f, 0.f};
            acc1[mi][ni] = f32x4{0.f, 0.f, 0.f, 0.f};
        }

    // ---- epilogue addressing (swapped C-map: row=l15 side, col=l4*4+r)
    // v4 index for (bn, mi, ni): row = bm*128 + wr*32 + mi*16 + l15,
    //                            colv4 = bn*16 + wc*8 + ni*4 + l4
    auto evi = [&](int bn, int mi, int ni) -> size_t {
        return (size_t)(bm * BM + wr * 32 + mi * 16 + l15) * (DIM / 4)
               + bn * 16 + wc * 8 + ni * 4 + l4;
    };

    f32x4 eX[2][2], eE[2][2], eW[2][2], tv[2];

    // T0 target (tiny, L2) loaded before stage(0)
#pragma unroll
    for (int ni = 0; ni < 2; ++ni)
        tv[ni] = ((const f32x4*)tgt)[bn0 * 16 + wc * 8 + ni * 4 + l4];

    auto stage = [&](int s) {                    // 3 glds per wave
        char* As = lds + (s % 3) * BUF;
        char* Bs = As + 16384;
        const char* gb = (s < 16) ? gB0 : gB1;
        const size_t ko = (size_t)((s < 16) ? s : s - 16) * (BK * 2);
#pragma unroll
        for (int j = 0; j < 2; ++j)
            __builtin_amdgcn_global_load_lds(
                AS1(gS + (size_t)j * (64 * DIM * 2) + ko),
                AS3(As + (wid * 8 + j * 64) * 128), 16, 0, 0);
        __builtin_amdgcn_global_load_lds(
            AS1(gb + ko), AS3(Bs + wid * 8 * 128), 16, 0, 0);
    };

    auto epiLoad = [&](int bn) {
#pragma unroll
        for (int mi = 0; mi < 2; ++mi)
#pragma unroll
            for (int ni = 0; ni < 2; ++ni) {
                const size_t v4 = evi(bn, mi, ni);
                eX[mi][ni] = ((const f32x4*)x)[v4];
                eE[mi][ni] = ((const f32x4*)ex)[v4];
                eW[mi][ni] = ((const f32x4*)W)[v4];
            }
    };

    auto epiStore = [&](int bn, f32x4 (&acc)[2][2]) {
#pragma unroll
        for (int mi = 0; mi < 2; ++mi)
#pragma unroll
            for (int ni = 0; ni < 2; ++ni) {
                const size_t v4 = evi(bn, mi, ni);
                f32x4 o0;
#pragma unroll
                for (int e = 0; e < 4; ++e) {
                    float xi = eX[mi][ni][e], ti = tv[ni][e];
                    float ba = ti * ti * __builtin_amdgcn_rcpf(1.0f + ti * ti);
                    float u  = -(eW[mi][ni][e] * (xi + eE[mi][ni][e] - ti)) * ba;
                    float sg = sigma_f(xi);
                    o0[e] = -xi + u * sg + acc[mi][ni][e];
                }
                ((f32x4*)out0)[v4] = o0;
                ((f32x4*)out1)[v4] = -o0;
            }
    };

    // ---- prologue
    stage(0);
    stage(1);

    // ---- continuous 32-step pipeline over both tiles
#pragma unroll
    for (int s = 0; s < 32; ++s) {
        __builtin_amdgcn_sched_barrier(0);
        if (s == 9 || s == 10)       asm volatile("s_waitcnt vmcnt(15)" ::: "memory");
        else if (s == 17 || s == 18) asm volatile("s_waitcnt vmcnt(11)" ::: "memory");
        else if (s == 25 || s == 26) asm volatile("s_waitcnt vmcnt(17)" ::: "memory");
        else if (s == 31)            asm volatile("s_waitcnt vmcnt(0)"  ::: "memory");
        else                         asm volatile("s_waitcnt vmcnt(3)"  ::: "memory");
        __builtin_amdgcn_sched_barrier(0);
        __builtin_amdgcn_s_barrier();
        __builtin_amdgcn_sched_barrier(0);
        if (s + 2 < 32) stage(s + 2);
        __builtin_amdgcn_sched_barrier(0);
        if (s == 8) epiLoad(bn0);                // lands by step 11 (vmcnt(3))
        if (s == 24) {                           // T1 reads + target
#pragma unroll
            for (int ni = 0; ni < 2; ++ni)
                tv[ni] = ((const f32x4*)tgt)[bn1 * 16 + wc * 8 + ni * 4 + l4];
            epiLoad(bn1);
        }
        if (s == 16) epiStore(bn0, acc0);        // hidden under T1 K-loop
        __builtin_amdgcn_sched_barrier(0);

        const char* As_ = lds + (s % 3) * BUF;
        const char* Bs_ = As_ + 16384;
#pragma unroll
        for (int kk = 0; kk < 2; ++kk) {
            bf16x8 af[2], bfr[2];
#pragma unroll
            for (int mi = 0; mi < 2; ++mi)
                af[mi] = *(const bf16x8*)(As_ + (wr * 32 + mi * 16 + l15) * 128 +
                                          ((cb0 + kk * 64) ^ rd_sw));
#pragma unroll
            for (int ni = 0; ni < 2; ++ni)
                bfr[ni] = *(const bf16x8*)(Bs_ + (wc * 32 + ni * 16 + l15) * 128 +
                                           ((cb0 + kk * 64) ^ rd_sw));
            if (s < 16) {
#pragma unroll
                for (int mi = 0; mi < 2; ++mi)
#pragma unroll
                    for (int ni = 0; ni < 2; ++ni)
                        acc0[mi][ni] = __builtin_amdgcn_mfma_f32_16x16x32_bf16(
                            bfr[ni], af[mi], acc0[mi][ni], 0, 0, 0);
            } else {
#pragma unroll
                for (int mi = 0; mi < 2; ++mi)
#pragma unroll
                    for (int ni = 0; ni < 2; ++ni)
                        acc1[mi][ni] = __builtin_amdgcn_mfma_f32_16x16x32_bf16(
                            bfr[ni], af[mi], acc1[mi][ni], 0, 0, 0);
            }
        }
    }

    // ---- T1 epilogue (E1/tv already resident; mfmas complete)
    epiStore(bn1, acc1);
}

// ---------------------------------------------------------------------------
extern "C" void kernel_launch(void* const* d_in, const int* in_sizes, int n_in,
                              void* d_out, int out_size, void* d_ws, size_t ws_size,
                              hipStream_t stream)
{
    const float* x   = (const float*)d_in[0];
    const float* ex  = (const float*)d_in[1];
    const float* W   = (const float*)d_in[2];
    const float* A   = (const float*)d_in[3];
    const float* tgt = (const float*)d_in[4];

    float* out0 = (float*)d_out;
    float* out1 = out0 + (size_t)BATCH * DIM;
    float* out2 = out1 + (size_t)BATCH * DIM;

    unsigned short* sigb = (unsigned short*)d_ws;                                   // 16 MiB
    unsigned short* Abf  = (unsigned short*)((char*)d_ws + (size_t)16 * 1024 * 1024); // 2 MiB

    prep_kernel<<<4608, 256, 0, stream>>>(x, A, sigb, Abf, out2);
    gemm_kernel<<<512, 512, 0, stream>>>(x, ex, W, tgt, sigb, Abf, out0, out1);
}

// Round 19
// 60.082 us; speedup vs baseline: 1.4655x; 1.4655x over previous
//
#include <hip/hip_runtime.h>
#include <hip/hip_bf16.h>
#include <stdint.h>

#define BATCH 8192
#define DIM   1024
#define BM 64
#define BN 64
#define BK 64
#define STEPS 16                 // DIM / BK
#define BUF 16384                // A 8K + B 8K per stage buffer

typedef __attribute__((ext_vector_type(4))) float f32x4;
typedef __attribute__((ext_vector_type(8))) short bf16x8;
typedef __attribute__((ext_vector_type(8))) unsigned short u16x8;

#define AS1(p) ((const __attribute__((address_space(1))) void*)(p))
#define AS3(p) ((__attribute__((address_space(3))) void*)(p))

__device__ __forceinline__ unsigned short f2bf(float f) {
    union { __hip_bfloat16 h; unsigned short u; } v;
    v.h = __hip_bfloat16(f);
    return v.u;
}
__device__ __forceinline__ float sigma_f(float x) {
    float x2 = x * x;
    return x2 * __builtin_amdgcn_rcpf(1.0f + x2);
}

// ---------------------------------------------------------------------------
// K1: sigma(x) -> bf16 ws (4096 blocks) | A -> bf16 (512 blocks)   [R13]
// ---------------------------------------------------------------------------
__global__ __launch_bounds__(256) void prep_kernel(
    const float* __restrict__ x, const float* __restrict__ A,
    unsigned short* __restrict__ sigb, unsigned short* __restrict__ Abf)
{
    const int i = blockIdx.x * 256 + threadIdx.x;
    if (i < BATCH * DIM / 8) {
        f32x4 v0 = ((const f32x4*)x)[i * 2];
        f32x4 v1 = ((const f32x4*)x)[i * 2 + 1];
        u16x8 sb;
#pragma unroll
        for (int e = 0; e < 4; ++e) {
            sb[e]     = f2bf(sigma_f(v0[e]));
            sb[e + 4] = f2bf(sigma_f(v1[e]));
        }
        ((u16x8*)sigb)[i] = sb;
    } else {
        const int j = i - BATCH * DIM / 8;       // < 131072
        f32x4 v0 = ((const f32x4*)A)[j * 2];
        f32x4 v1 = ((const f32x4*)A)[j * 2 + 1];
        u16x8 ab;
#pragma unroll
        for (int e = 0; e < 4; ++e) {
            ab[e]     = f2bf(v0[e]);
            ab[e + 4] = f2bf(v1[e]);
        }
        ((u16x8*)Abf)[j] = ab;
    }
}

// ---------------------------------------------------------------------------
// K2: GEMM 64x64 tile, 3 barrier domains per CU (48 KiB LDS, 3 blocks/CU).
//   2048 blocks, 256 thr (4 waves, 2x2: 32x32/wave, acc[2][2]).
//   R13 counted-vmcnt/raw-barrier pipeline (4 glds/wave/stage, depth 2)
//   + R16 epilogue register prefetch. VMEM ISSUE ORDER PINNED with
//   sched_barrier(0) after stage(0), stage(1), and the epi prefetch
//   (R18's NaN was compiler-reordered issue order breaking the ledger).
//   vmcnt ledger: [s0(4), s1(4), epi(16)]; waits 20,20,4,...,4,0.
// ---------------------------------------------------------------------------
__global__ __launch_bounds__(256, 3) void gemm_kernel(
    const float* __restrict__ x, const float* __restrict__ ex,
    const float* __restrict__ W, const float* __restrict__ tgt,
    const unsigned short* __restrict__ sigb,
    const unsigned short* __restrict__ Abf,
    float* __restrict__ out0, float* __restrict__ out1,
    float* __restrict__ out2)
{
    __shared__ __align__(16) char lds[3 * BUF];

    // ---- block mapping: 16 bms per XCD (sig panel slice 2 MB -> L2 fit)
    const int b     = blockIdx.x;
    const int xcd   = b & 7;
    const int local = b >> 3;                    // 0..255
    const int bm    = xcd * 16 + (local >> 4);   // 0..127
    const int bn    = local & 15;                // 0..15

    const int tid  = threadIdx.x;
    const int lane = tid & 63;
    const int wid  = tid >> 6;                   // 0..3
    const int wr   = wid >> 1, wc = wid & 1;     // 2x2 wave grid
    const int l15  = lane & 15;

    // ---- staging sources (pre-swizzled source, linear LDS dest; R13 algebra)
    const int swz = (((lane & 7) ^ (lane >> 3)) << 4);
    const char* gS = (const char*)sigb +
        ((size_t)(bm * BM + wid * 16 + (lane >> 3)) * DIM) * 2 + swz;
    const char* gB = (const char*)Abf +
        ((size_t)(bn * BN + wid * 16 + (lane >> 3)) * DIM) * 2 + swz;

    // ---- fragment read constants (R13-verified, 128 B rows)
    const int rd_sw = (lane & 7) << 4;
    const int cb0   = (lane >> 4) << 4;

    f32x4 acc[2][2];
#pragma unroll
    for (int mi = 0; mi < 2; ++mi)
#pragma unroll
        for (int ni = 0; ni < 2; ++ni)
            acc[mi][ni] = f32x4{0.f, 0.f, 0.f, 0.f};

    auto stage = [&](int t) {                    // 4 glds per wave
        char* As = lds + (t % 3) * BUF;
        char* Bs = As + 8192;
        const size_t ko = (size_t)t * (BK * 2);
#pragma unroll
        for (int j = 0; j < 2; ++j)
            __builtin_amdgcn_global_load_lds(
                AS1(gS + (size_t)j * (8 * DIM * 2) + ko),
                AS3(As + (wid * 16 + j * 8) * 128), 16, 0, 0);
#pragma unroll
        for (int j = 0; j < 2; ++j)
            __builtin_amdgcn_global_load_lds(
                AS1(gB + (size_t)j * (8 * DIM * 2) + ko),
                AS3(Bs + (wid * 16 + j * 8) * 128), 16, 0, 0);
    };

    // ---- prologue: two stages in flight, then epi prefetch — ORDER PINNED
    stage(0);
    __builtin_amdgcn_sched_barrier(0);
    stage(1);
    __builtin_amdgcn_sched_barrier(0);

    f32x4 eX[4], eE[4], eW[4], tv[4];
#pragma unroll
    for (int p = 0; p < 4; ++p) {
        const int ci  = p * 256 + tid;           // 0..1023
        const int row = ci >> 4;                 // 0..63
        const int cv  = ci & 15;                 // 0..15
        const size_t v4 = (size_t)(bm * BM + row) * (DIM / 4) + bn * 16 + cv;
        eX[p] = ((const f32x4*)x)[v4];
        eE[p] = ((const f32x4*)ex)[v4];
        eW[p] = ((const f32x4*)W)[v4];
        tv[p] = ((const f32x4*)tgt)[bn * 16 + cv];
    }
    __builtin_amdgcn_sched_barrier(0);

    // ---- main loop: counted wait + raw barrier per step
    for (int t = 0; t < STEPS; ++t) {
        __builtin_amdgcn_sched_barrier(0);
        if (t < 2)              asm volatile("s_waitcnt vmcnt(20)" ::: "memory");
        else if (t < STEPS - 1) asm volatile("s_waitcnt vmcnt(4)"  ::: "memory");
        else                    asm volatile("s_waitcnt vmcnt(0)"  ::: "memory");
        __builtin_amdgcn_sched_barrier(0);
        __builtin_amdgcn_s_barrier();
        __builtin_amdgcn_sched_barrier(0);
        if (t + 2 < STEPS) stage(t + 2);
        __builtin_amdgcn_sched_barrier(0);

        const char* As_ = lds + (t % 3) * BUF;
        const char* Bs_ = As_ + 8192;
#pragma unroll
        for (int kk = 0; kk < 2; ++kk) {
            bf16x8 af[2], bfr[2];
#pragma unroll
            for (int mi = 0; mi < 2; ++mi)
                af[mi] = *(const bf16x8*)(As_ + (wr * 32 + mi * 16 + l15) * 128 +
                                          ((cb0 + kk * 64) ^ rd_sw));
#pragma unroll
            for (int ni = 0; ni < 2; ++ni)
                bfr[ni] = *(const bf16x8*)(Bs_ + (wc * 32 + ni * 16 + l15) * 128 +
                                           ((cb0 + kk * 64) ^ rd_sw));
#pragma unroll
            for (int mi = 0; mi < 2; ++mi)
#pragma unroll
                for (int ni = 0; ni < 2; ++ni)
                    acc[mi][ni] = __builtin_amdgcn_mfma_f32_16x16x32_bf16(
                        af[mi], bfr[ni], acc[mi][ni], 0, 0, 0);
        }
    }

    // ---- epilogue: C -> LDS f32[64][64] (linear, 256 B rows), then stream
    __syncthreads();
#pragma unroll
    for (int mi = 0; mi < 2; ++mi)
#pragma unroll
        for (int ni = 0; ni < 2; ++ni) {
            const int row_ = wr * 32 + mi * 16 + ((lane >> 4) << 2);
            const int colb = (wc * 32 + ni * 16 + l15) * 4;
#pragma unroll
            for (int r = 0; r < 4; ++r)
                *(float*)(lds + (row_ + r) * 256 + colb) = acc[mi][ni][r];
        }
    __syncthreads();

#pragma unroll
    for (int p = 0; p < 4; ++p) {
        const int ci  = p * 256 + tid;           // 0..1023
        const int row = ci >> 4;                 // 0..63
        const int cv  = ci & 15;                 // 0..15
        f32x4 c = *(const f32x4*)(lds + row * 256 + cv * 16);
        const size_t v4 = (size_t)(bm * BM + row) * (DIM / 4) + bn * 16 + cv;
        f32x4 o0;
#pragma unroll
        for (int e = 0; e < 4; ++e) {
            float xi = eX[p][e], ti = tv[p][e];
            float ba = ti * ti * __builtin_amdgcn_rcpf(1.0f + ti * ti);
            float u  = -(eW[p][e] * (xi + eE[p][e] - ti)) * ba;
            float s  = sigma_f(xi);
            o0[e] = -xi + u * s + c[e];
        }
        ((f32x4*)out0)[v4] = o0;
        ((f32x4*)out1)[v4] = -o0;
        ((f32x4*)out2)[v4] = f32x4{0.f, 0.f, 0.f, 0.f};
    }
}

// ---------------------------------------------------------------------------
extern "C" void kernel_launch(void* const* d_in, const int* in_sizes, int n_in,
                              void* d_out, int out_size, void* d_ws, size_t ws_size,
                              hipStream_t stream)
{
    const float* x   = (const float*)d_in[0];
    const float* ex  = (const float*)d_in[1];
    const float* W   = (const float*)d_in[2];
    const float* A   = (const float*)d_in[3];
    const float* tgt = (const float*)d_in[4];

    float* out0 = (float*)d_out;
    float* out1 = out0 + (size_t)BATCH * DIM;
    float* out2 = out1 + (size_t)BATCH * DIM;

    unsigned short* sigb = (unsigned short*)d_ws;                                   // 16 MiB
    unsigned short* Abf  = (unsigned short*)((char*)d_ws + (size_t)16 * 1024 * 1024); // 2 MiB

    prep_kernel<<<4608, 256, 0, stream>>>(x, A, sigb, Abf);
    gemm_kernel<<<(BATCH / BM) * (DIM / BN), 256, 0, stream>>>(
        x, ex, W, tgt, sigb, Abf, out0, out1, out2);
}

// Round 20
// 56.639 us; speedup vs baseline: 1.5545x; 1.0608x over previous
//
#include <hip/hip_runtime.h>
#include <hip/hip_bf16.h>
#include <stdint.h>

#define BATCH 8192
#define DIM   1024
#define BM 128
#define BN 64
#define BK 64
#define STEPS 16                 // DIM / BK
#define BUF 24576                // A 16K + B 8K per stage buffer

typedef __attribute__((ext_vector_type(4))) float f32x4;
typedef __attribute__((ext_vector_type(8))) short bf16x8;
typedef __attribute__((ext_vector_type(8))) unsigned short u16x8;

#define AS1(p) ((const __attribute__((address_space(1))) void*)(p))
#define AS3(p) ((__attribute__((address_space(3))) void*)(p))

__device__ __forceinline__ unsigned short f2bf(float f) {
    union { __hip_bfloat16 h; unsigned short u; } v;
    v.h = __hip_bfloat16(f);
    return v.u;
}
__device__ __forceinline__ float sigma_f(float x) {
    float x2 = x * x;
    return x2 * __builtin_amdgcn_rcpf(1.0f + x2);
}

// ---------------------------------------------------------------------------
// K1: sigma(x) -> bf16 ws (4096 blocks) | A -> bf16 (512 blocks)   [R13]
// ---------------------------------------------------------------------------
__global__ __launch_bounds__(256) void prep_kernel(
    const float* __restrict__ x, const float* __restrict__ A,
    unsigned short* __restrict__ sigb, unsigned short* __restrict__ Abf)
{
    const int i = blockIdx.x * 256 + threadIdx.x;
    if (i < BATCH * DIM / 8) {
        f32x4 v0 = ((const f32x4*)x)[i * 2];
        f32x4 v1 = ((const f32x4*)x)[i * 2 + 1];
        u16x8 sb;
#pragma unroll
        for (int e = 0; e < 4; ++e) {
            sb[e]     = f2bf(sigma_f(v0[e]));
            sb[e + 4] = f2bf(sigma_f(v1[e]));
        }
        ((u16x8*)sigb)[i] = sb;
    } else {
        const int j = i - BATCH * DIM / 8;       // < 131072
        f32x4 v0 = ((const f32x4*)A)[j * 2];
        f32x4 v1 = ((const f32x4*)A)[j * 2 + 1];
        u16x8 ab;
#pragma unroll
        for (int e = 0; e < 4; ++e) {
            ab[e]     = f2bf(v0[e]);
            ab[e + 4] = f2bf(v1[e]);
        }
        ((u16x8*)Abf)[j] = ab;
    }
}

// ---------------------------------------------------------------------------
// K2: R16's gemm (best measured: 128x64, 512 thr, 3-stage counted-vmcnt,
//   pinned epilogue register prefetch) + out2 stores + tgt in the prefetch.
//   vmcnt ledger: [s0(3), s1(3), epi(16)] -> waits 19,19,3,...,3,0.
//   8 waves (4x2 grid, 32x32/wave, acc[2][2]); LDS 72K; 2 blocks/CU.
// ---------------------------------------------------------------------------
__global__ __launch_bounds__(512, 4) void gemm_kernel(
    const float* __restrict__ x, const float* __restrict__ ex,
    const float* __restrict__ W, const float* __restrict__ tgt,
    const unsigned short* __restrict__ sigb,
    const unsigned short* __restrict__ Abf,
    float* __restrict__ out0, float* __restrict__ out1,
    float* __restrict__ out2)
{
    __shared__ __align__(16) char lds[3 * BUF];

    // ---- block mapping: same-bm blocks share an XCD (sigb/x L2 reuse)
    const int b     = blockIdx.x;
    const int xcd   = b & 7;
    const int local = b >> 3;                    // 0..127
    const int bm    = xcd * 8 + (local >> 4);    // 0..63
    const int bn    = local & 15;                // 0..15

    const int tid  = threadIdx.x;
    const int lane = tid & 63;
    const int wid  = tid >> 6;                   // 0..7
    const int wr   = wid >> 1, wc = wid & 1;     // 4x2 wave grid
    const int l15  = lane & 15;

    // ---- staging sources (pre-swizzled source, linear LDS dest; R13 algebra)
    const int swz = (((lane & 7) ^ (lane >> 3)) << 4);
    const char* gS = (const char*)sigb +
        ((size_t)(bm * BM + wid * 8 + (lane >> 3)) * DIM) * 2 + swz;
    const char* gB = (const char*)Abf +
        ((size_t)(bn * BN + wid * 8 + (lane >> 3)) * DIM) * 2 + swz;

    // ---- fragment read constants
    const int rd_sw = (lane & 7) << 4;
    const int cb0   = (lane >> 4) << 4;

    f32x4 acc[2][2];
#pragma unroll
    for (int mi = 0; mi < 2; ++mi)
#pragma unroll
        for (int ni = 0; ni < 2; ++ni)
            acc[mi][ni] = f32x4{0.f, 0.f, 0.f, 0.f};

    auto stage = [&](int t) {                    // 3 glds per wave
        char* As = lds + (t % 3) * BUF;
        char* Bs = As + 16384;
        const size_t ko = (size_t)t * (BK * 2);
#pragma unroll
        for (int j = 0; j < 2; ++j)
            __builtin_amdgcn_global_load_lds(
                AS1(gS + (size_t)j * (64 * DIM * 2) + ko),
                AS3(As + (wid * 8 + j * 64) * 128), 16, 0, 0);
        __builtin_amdgcn_global_load_lds(
            AS1(gB + ko), AS3(Bs + wid * 8 * 128), 16, 0, 0);
    };

    // ---- prologue: two stages, then epi prefetch — ISSUE ORDER PINNED
    stage(0);
    __builtin_amdgcn_sched_barrier(0);
    stage(1);
    __builtin_amdgcn_sched_barrier(0);

    f32x4 eX[4], eE[4], eW[4], tv[4];
#pragma unroll
    for (int p = 0; p < 4; ++p) {
        const int ci  = p * 512 + tid;           // 0..2047
        const int row = ci >> 4;                 // 0..127
        const int cv  = ci & 15;                 // 0..15
        const size_t v4 = (size_t)(bm * BM + row) * (DIM / 4) + bn * 16 + cv;
        eX[p] = ((const f32x4*)x)[v4];
        eE[p] = ((const f32x4*)ex)[v4];
        eW[p] = ((const f32x4*)W)[v4];
        tv[p] = ((const f32x4*)tgt)[bn * 16 + cv];
    }
    __builtin_amdgcn_sched_barrier(0);

    // ---- main loop: counted wait + raw barrier per step
    for (int t = 0; t < STEPS; ++t) {
        __builtin_amdgcn_sched_barrier(0);
        if (t < 2)              asm volatile("s_waitcnt vmcnt(19)" ::: "memory");
        else if (t < STEPS - 1) asm volatile("s_waitcnt vmcnt(3)"  ::: "memory");
        else                    asm volatile("s_waitcnt vmcnt(0)"  ::: "memory");
        __builtin_amdgcn_sched_barrier(0);
        __builtin_amdgcn_s_barrier();
        __builtin_amdgcn_sched_barrier(0);
        if (t + 2 < STEPS) stage(t + 2);
        __builtin_amdgcn_sched_barrier(0);

        const char* As_ = lds + (t % 3) * BUF;
        const char* Bs_ = As_ + 16384;
#pragma unroll
        for (int kk = 0; kk < 2; ++kk) {
            bf16x8 af[2], bfr[2];
#pragma unroll
            for (int mi = 0; mi < 2; ++mi)
                af[mi] = *(const bf16x8*)(As_ + (wr * 32 + mi * 16 + l15) * 128 +
                                          ((cb0 + kk * 64) ^ rd_sw));
#pragma unroll
            for (int ni = 0; ni < 2; ++ni)
                bfr[ni] = *(const bf16x8*)(Bs_ + (wc * 32 + ni * 16 + l15) * 128 +
                                           ((cb0 + kk * 64) ^ rd_sw));
#pragma unroll
            for (int mi = 0; mi < 2; ++mi)
#pragma unroll
                for (int ni = 0; ni < 2; ++ni)
                    acc[mi][ni] = __builtin_amdgcn_mfma_f32_16x16x32_bf16(
                        af[mi], bfr[ni], acc[mi][ni], 0, 0, 0);
        }
    }

    // ---- epilogue: C -> LDS f32[128][64] (linear), then register epilogue
    __syncthreads();
#pragma unroll
    for (int mi = 0; mi < 2; ++mi)
#pragma unroll
        for (int ni = 0; ni < 2; ++ni) {
            const int row_ = wr * 32 + mi * 16 + ((lane >> 4) << 2);
            const int colb = (wc * 32 + ni * 16 + l15) * 4;
#pragma unroll
            for (int r = 0; r < 4; ++r)
                *(float*)(lds + (row_ + r) * 256 + colb) = acc[mi][ni][r];
        }
    __syncthreads();

#pragma unroll
    for (int p = 0; p < 4; ++p) {
        const int ci  = p * 512 + tid;           // 0..2047
        const int row = ci >> 4;                 // 0..127
        const int cv  = ci & 15;                 // 0..15
        f32x4 c = *(const f32x4*)(lds + row * 256 + cv * 16);
        const size_t v4 = (size_t)(bm * BM + row) * (DIM / 4) + bn * 16 + cv;
        f32x4 o0;
#pragma unroll
        for (int e = 0; e < 4; ++e) {
            float xi = eX[p][e], ti = tv[p][e];
            float ba = ti * ti * __builtin_amdgcn_rcpf(1.0f + ti * ti);
            float u  = -(eW[p][e] * (xi + eE[p][e] - ti)) * ba;
            float s  = sigma_f(xi);
            o0[e] = -xi + u * s + c[e];
        }
        ((f32x4*)out0)[v4] = o0;
        ((f32x4*)out1)[v4] = -o0;
        ((f32x4*)out2)[v4] = f32x4{0.f, 0.f, 0.f, 0.f};
    }
}

// ---------------------------------------------------------------------------
extern "C" void kernel_launch(void* const* d_in, const int* in_sizes, int n_in,
                              void* d_out, int out_size, void* d_ws, size_t ws_size,
                              hipStream_t stream)
{
    const float* x   = (const float*)d_in[0];
    const float* ex  = (const float*)d_in[1];
    const float* W   = (const float*)d_in[2];
    const float* A   = (const float*)d_in[3];
    const float* tgt = (const float*)d_in[4];

    float* out0 = (float*)d_out;
    float* out1 = out0 + (size_t)BATCH * DIM;
    float* out2 = out1 + (size_t)BATCH * DIM;

    unsigned short* sigb = (unsigned short*)d_ws;                                   // 16 MiB
    unsigned short* Abf  = (unsigned short*)((char*)d_ws + (size_t)16 * 1024 * 1024); // 2 MiB

    prep_kernel<<<4608, 256, 0, stream>>>(x, A, sigb, Abf);
    gemm_kernel<<<(BATCH / BM) * (DIM / BN), 512, 0, stream>>>(
        x, ex, W, tgt, sigb, Abf, out0, out1, out2);
}

// Round 21
// 55.505 us; speedup vs baseline: 1.5863x; 1.0204x over previous
//
#include <hip/hip_runtime.h>
#include <hip/hip_bf16.h>
#include <stdint.h>

#define BATCH 8192
#define DIM   1024
#define BM 128
#define BN 64
#define BK 64
#define STEPS 16                 // DIM / BK
#define BUF 24576                // A 16K + B 8K per stage buffer

typedef __attribute__((ext_vector_type(4))) float f32x4;
typedef __attribute__((ext_vector_type(8))) short bf16x8;
typedef __attribute__((ext_vector_type(8))) unsigned short u16x8;

#define AS1(p) ((const __attribute__((address_space(1))) void*)(p))
#define AS3(p) ((__attribute__((address_space(3))) void*)(p))

__device__ __forceinline__ unsigned short f2bf(float f) {
    union { __hip_bfloat16 h; unsigned short u; } v;
    v.h = __hip_bfloat16(f);
    return v.u;
}
__device__ __forceinline__ float sigma_f(float x) {
    float x2 = x * x;
    return x2 * __builtin_amdgcn_rcpf(1.0f + x2);
}

// ---------------------------------------------------------------------------
// K1: sigma(x) -> bf16 ws (4096 blocks) | A -> bf16 (512 blocks)   [R13]
// ---------------------------------------------------------------------------
__global__ __launch_bounds__(256) void prep_kernel(
    const float* __restrict__ x, const float* __restrict__ A,
    unsigned short* __restrict__ sigb, unsigned short* __restrict__ Abf)
{
    const int i = blockIdx.x * 256 + threadIdx.x;
    if (i < BATCH * DIM / 8) {
        f32x4 v0 = ((const f32x4*)x)[i * 2];
        f32x4 v1 = ((const f32x4*)x)[i * 2 + 1];
        u16x8 sb;
#pragma unroll
        for (int e = 0; e < 4; ++e) {
            sb[e]     = f2bf(sigma_f(v0[e]));
            sb[e + 4] = f2bf(sigma_f(v1[e]));
        }
        ((u16x8*)sigb)[i] = sb;
    } else {
        const int j = i - BATCH * DIM / 8;       // < 131072
        f32x4 v0 = ((const f32x4*)A)[j * 2];
        f32x4 v1 = ((const f32x4*)A)[j * 2 + 1];
        u16x8 ab;
#pragma unroll
        for (int e = 0; e < 4; ++e) {
            ab[e]     = f2bf(v0[e]);
            ab[e + 4] = f2bf(v1[e]);
        }
        ((u16x8*)Abf)[j] = ab;
    }
}

// ---------------------------------------------------------------------------
// K2: R20 gemm (128x64, 512 thr, 3-stage counted-vmcnt, pinned epi prefetch)
//   + out2-zero stores INSIDE the K-loop (steps 0-3, 1 v4/thread/step):
//   the loop has idle HBM-write BW; stores join the vmcnt ledger.
//   Issue order: s0(3), s1(3), epi(16); per step: stage(t+2)(3), z(t)(t<4).
//   Hand-simulated waits: t0:19 t1:20 t2-4:5 t5:4 t6-14:3 t15:0.
//   Epilogue writes out0/out1 only (out2 done in-loop).
// ---------------------------------------------------------------------------
__global__ __launch_bounds__(512, 4) void gemm_kernel(
    const float* __restrict__ x, const float* __restrict__ ex,
    const float* __restrict__ W, const float* __restrict__ tgt,
    const unsigned short* __restrict__ sigb,
    const unsigned short* __restrict__ Abf,
    float* __restrict__ out0, float* __restrict__ out1,
    float* __restrict__ out2)
{
    __shared__ __align__(16) char lds[3 * BUF];

    // ---- block mapping: same-bm blocks share an XCD (sigb/x L2 reuse)
    const int b     = blockIdx.x;
    const int xcd   = b & 7;
    const int local = b >> 3;                    // 0..127
    const int bm    = xcd * 8 + (local >> 4);    // 0..63
    const int bn    = local & 15;                // 0..15

    const int tid  = threadIdx.x;
    const int lane = tid & 63;
    const int wid  = tid >> 6;                   // 0..7
    const int wr   = wid >> 1, wc = wid & 1;     // 4x2 wave grid
    const int l15  = lane & 15;

    // ---- staging sources (pre-swizzled source, linear LDS dest; R13 algebra)
    const int swz = (((lane & 7) ^ (lane >> 3)) << 4);
    const char* gS = (const char*)sigb +
        ((size_t)(bm * BM + wid * 8 + (lane >> 3)) * DIM) * 2 + swz;
    const char* gB = (const char*)Abf +
        ((size_t)(bn * BN + wid * 8 + (lane >> 3)) * DIM) * 2 + swz;

    // ---- fragment read constants
    const int rd_sw = (lane & 7) << 4;
    const int cb0   = (lane >> 4) << 4;

    // ---- epilogue / zero-store addressing (p = 0..3)
    auto evi = [&](int p) -> size_t {
        const int ci  = p * 512 + tid;           // 0..2047
        const int row = ci >> 4;                 // 0..127
        const int cv  = ci & 15;                 // 0..15
        return (size_t)(bm * BM + row) * (DIM / 4) + bn * 16 + cv;
    };

    f32x4 acc[2][2];
#pragma unroll
    for (int mi = 0; mi < 2; ++mi)
#pragma unroll
        for (int ni = 0; ni < 2; ++ni)
            acc[mi][ni] = f32x4{0.f, 0.f, 0.f, 0.f};

    auto stage = [&](int t) {                    // 3 glds per wave
        char* As = lds + (t % 3) * BUF;
        char* Bs = As + 16384;
        const size_t ko = (size_t)t * (BK * 2);
#pragma unroll
        for (int j = 0; j < 2; ++j)
            __builtin_amdgcn_global_load_lds(
                AS1(gS + (size_t)j * (64 * DIM * 2) + ko),
                AS3(As + (wid * 8 + j * 64) * 128), 16, 0, 0);
        __builtin_amdgcn_global_load_lds(
            AS1(gB + ko), AS3(Bs + wid * 8 * 128), 16, 0, 0);
    };

    // ---- prologue: two stages, then epi prefetch — ISSUE ORDER PINNED
    stage(0);
    __builtin_amdgcn_sched_barrier(0);
    stage(1);
    __builtin_amdgcn_sched_barrier(0);

    f32x4 eX[4], eE[4], eW[4], tv[4];
#pragma unroll
    for (int p = 0; p < 4; ++p) {
        const size_t v4 = evi(p);
        const int cv = (p * 512 + tid) & 15;
        eX[p] = ((const f32x4*)x)[v4];
        eE[p] = ((const f32x4*)ex)[v4];
        eW[p] = ((const f32x4*)W)[v4];
        tv[p] = ((const f32x4*)tgt)[bn * 16 + cv];
    }
    __builtin_amdgcn_sched_barrier(0);

    // ---- main loop: counted wait + raw barrier per step
    for (int t = 0; t < STEPS; ++t) {
        __builtin_amdgcn_sched_barrier(0);
        if (t == 0)             asm volatile("s_waitcnt vmcnt(19)" ::: "memory");
        else if (t == 1)        asm volatile("s_waitcnt vmcnt(20)" ::: "memory");
        else if (t <= 4)        asm volatile("s_waitcnt vmcnt(5)"  ::: "memory");
        else if (t == 5)        asm volatile("s_waitcnt vmcnt(4)"  ::: "memory");
        else if (t < STEPS - 1) asm volatile("s_waitcnt vmcnt(3)"  ::: "memory");
        else                    asm volatile("s_waitcnt vmcnt(0)"  ::: "memory");
        __builtin_amdgcn_sched_barrier(0);
        __builtin_amdgcn_s_barrier();
        __builtin_amdgcn_sched_barrier(0);
        if (t + 2 < STEPS) stage(t + 2);
        __builtin_amdgcn_sched_barrier(0);
        if (t < 4)   // out2 zeros ride the loop's idle write pipe
            ((f32x4*)out2)[evi(t)] = f32x4{0.f, 0.f, 0.f, 0.f};
        __builtin_amdgcn_sched_barrier(0);

        const char* As_ = lds + (t % 3) * BUF;
        const char* Bs_ = As_ + 16384;
#pragma unroll
        for (int kk = 0; kk < 2; ++kk) {
            bf16x8 af[2], bfr[2];
#pragma unroll
            for (int mi = 0; mi < 2; ++mi)
                af[mi] = *(const bf16x8*)(As_ + (wr * 32 + mi * 16 + l15) * 128 +
                                          ((cb0 + kk * 64) ^ rd_sw));
#pragma unroll
            for (int ni = 0; ni < 2; ++ni)
                bfr[ni] = *(const bf16x8*)(Bs_ + (wc * 32 + ni * 16 + l15) * 128 +
                                           ((cb0 + kk * 64) ^ rd_sw));
#pragma unroll
            for (int mi = 0; mi < 2; ++mi)
#pragma unroll
                for (int ni = 0; ni < 2; ++ni)
                    acc[mi][ni] = __builtin_amdgcn_mfma_f32_16x16x32_bf16(
                        af[mi], bfr[ni], acc[mi][ni], 0, 0, 0);
        }
    }

    // ---- epilogue: C -> LDS f32[128][64] (linear), then register epilogue
    __syncthreads();
#pragma unroll
    for (int mi = 0; mi < 2; ++mi)
#pragma unroll
        for (int ni = 0; ni < 2; ++ni) {
            const int row_ = wr * 32 + mi * 16 + ((lane >> 4) << 2);
            const int colb = (wc * 32 + ni * 16 + l15) * 4;
#pragma unroll
            for (int r = 0; r < 4; ++r)
                *(float*)(lds + (row_ + r) * 256 + colb) = acc[mi][ni][r];
        }
    __syncthreads();

#pragma unroll
    for (int p = 0; p < 4; ++p) {
        const int ci  = p * 512 + tid;           // 0..2047
        const int row = ci >> 4;                 // 0..127
        const int cv  = ci & 15;                 // 0..15
        f32x4 c = *(const f32x4*)(lds + row * 256 + cv * 16);
        const size_t v4 = (size_t)(bm * BM + row) * (DIM / 4) + bn * 16 + cv;
        f32x4 o0;
#pragma unroll
        for (int e = 0; e < 4; ++e) {
            float xi = eX[p][e], ti = tv[p][e];
            float ba = ti * ti * __builtin_amdgcn_rcpf(1.0f + ti * ti);
            float u  = -(eW[p][e] * (xi + eE[p][e] - ti)) * ba;
            float s  = sigma_f(xi);
            o0[e] = -xi + u * s + c[e];
        }
        ((f32x4*)out0)[v4] = o0;
        ((f32x4*)out1)[v4] = -o0;
    }
}

// ---------------------------------------------------------------------------
extern "C" void kernel_launch(void* const* d_in, const int* in_sizes, int n_in,
                              void* d_out, int out_size, void* d_ws, size_t ws_size,
                              hipStream_t stream)
{
    const float* x   = (const float*)d_in[0];
    const float* ex  = (const float*)d_in[1];
    const float* W   = (const float*)d_in[2];
    const float* A   = (const float*)d_in[3];
    const float* tgt = (const float*)d_in[4];

    float* out0 = (float*)d_out;
    float* out1 = out0 + (size_t)BATCH * DIM;
    float* out2 = out1 + (size_t)BATCH * DIM;

    unsigned short* sigb = (unsigned short*)d_ws;                                   // 16 MiB
    unsigned short* Abf  = (unsigned short*)((char*)d_ws + (size_t)16 * 1024 * 1024); // 2 MiB

    prep_kernel<<<4608, 256, 0, stream>>>(x, A, sigb, Abf);
    gemm_kernel<<<(BATCH / BM) * (DIM / BN), 512, 0, stream>>>(
        x, ex, W, tgt, sigb, Abf, out0, out1, out2);
}

// Round 22
// 55.395 us; speedup vs baseline: 1.5894x; 1.0020x over previous
//
#include <hip/hip_runtime.h>
#include <hip/hip_bf16.h>
#include <stdint.h>

#define BATCH 8192
#define DIM   1024
#define BM 128
#define BN 64
#define BK 64
#define STEPS 16                 // DIM / BK
#define BUF 24576                // A 16K + B 8K per stage buffer

typedef __attribute__((ext_vector_type(4))) float f32x4;
typedef __attribute__((ext_vector_type(8))) short bf16x8;
typedef __attribute__((ext_vector_type(8))) unsigned short u16x8;

#define AS1(p) ((const __attribute__((address_space(1))) void*)(p))
#define AS3(p) ((__attribute__((address_space(3))) void*)(p))

__device__ __forceinline__ unsigned short f2bf(float f) {
    union { __hip_bfloat16 h; unsigned short u; } v;
    v.h = __hip_bfloat16(f);
    return v.u;
}
__device__ __forceinline__ float sigma_f(float x) {
    float x2 = x * x;
    return x2 * __builtin_amdgcn_rcpf(1.0f + x2);
}

// ---------------------------------------------------------------------------
// K1: sigma(x) -> bf16 ws (4096 blocks) | A -> bf16 (512 blocks)   [R13]
// ---------------------------------------------------------------------------
__global__ __launch_bounds__(256) void prep_kernel(
    const float* __restrict__ x, const float* __restrict__ A,
    unsigned short* __restrict__ sigb, unsigned short* __restrict__ Abf)
{
    const int i = blockIdx.x * 256 + threadIdx.x;
    if (i < BATCH * DIM / 8) {
        f32x4 v0 = ((const f32x4*)x)[i * 2];
        f32x4 v1 = ((const f32x4*)x)[i * 2 + 1];
        u16x8 sb;
#pragma unroll
        for (int e = 0; e < 4; ++e) {
            sb[e]     = f2bf(sigma_f(v0[e]));
            sb[e + 4] = f2bf(sigma_f(v1[e]));
        }
        ((u16x8*)sigb)[i] = sb;
    } else {
        const int j = i - BATCH * DIM / 8;       // < 131072
        f32x4 v0 = ((const f32x4*)A)[j * 2];
        f32x4 v1 = ((const f32x4*)A)[j * 2 + 1];
        u16x8 ab;
#pragma unroll
        for (int e = 0; e < 4; ++e) {
            ab[e]     = f2bf(v0[e]);
            ab[e + 4] = f2bf(v1[e]);
        }
        ((u16x8*)Abf)[j] = ab;
    }
}

// ---------------------------------------------------------------------------
// K2: R21 gemm (128x64, 512 thr, 3-stage counted-vmcnt, pinned epi prefetch,
//   in-loop out2 zeros) + T5: s_setprio(1) around the MFMA cluster.
//   Mechanism: 2 blocks/CU at independent barrier phases -> when one block
//   stalls on vmcnt, the other's MFMA-entering waves get issue priority.
//   vmcnt ledger unchanged: s0(3), s1(3), epi(16); z(t) t<4;
//   waits t0:19 t1:20 t2-4:5 t5:4 t6-14:3 t15:0.
// ---------------------------------------------------------------------------
__global__ __launch_bounds__(512, 4) void gemm_kernel(
    const float* __restrict__ x, const float* __restrict__ ex,
    const float* __restrict__ W, const float* __restrict__ tgt,
    const unsigned short* __restrict__ sigb,
    const unsigned short* __restrict__ Abf,
    float* __restrict__ out0, float* __restrict__ out1,
    float* __restrict__ out2)
{
    __shared__ __align__(16) char lds[3 * BUF];

    // ---- block mapping: same-bm blocks share an XCD (sigb/x L2 reuse)
    const int b     = blockIdx.x;
    const int xcd   = b & 7;
    const int local = b >> 3;                    // 0..127
    const int bm    = xcd * 8 + (local >> 4);    // 0..63
    const int bn    = local & 15;                // 0..15

    const int tid  = threadIdx.x;
    const int lane = tid & 63;
    const int wid  = tid >> 6;                   // 0..7
    const int wr   = wid >> 1, wc = wid & 1;     // 4x2 wave grid
    const int l15  = lane & 15;

    // ---- staging sources (pre-swizzled source, linear LDS dest; R13 algebra)
    const int swz = (((lane & 7) ^ (lane >> 3)) << 4);
    const char* gS = (const char*)sigb +
        ((size_t)(bm * BM + wid * 8 + (lane >> 3)) * DIM) * 2 + swz;
    const char* gB = (const char*)Abf +
        ((size_t)(bn * BN + wid * 8 + (lane >> 3)) * DIM) * 2 + swz;

    // ---- fragment read constants
    const int rd_sw = (lane & 7) << 4;
    const int cb0   = (lane >> 4) << 4;

    // ---- epilogue / zero-store addressing (p = 0..3)
    auto evi = [&](int p) -> size_t {
        const int ci  = p * 512 + tid;           // 0..2047
        const int row = ci >> 4;                 // 0..127
        const int cv  = ci & 15;                 // 0..15
        return (size_t)(bm * BM + row) * (DIM / 4) + bn * 16 + cv;
    };

    f32x4 acc[2][2];
#pragma unroll
    for (int mi = 0; mi < 2; ++mi)
#pragma unroll
        for (int ni = 0; ni < 2; ++ni)
            acc[mi][ni] = f32x4{0.f, 0.f, 0.f, 0.f};

    auto stage = [&](int t) {                    // 3 glds per wave
        char* As = lds + (t % 3) * BUF;
        char* Bs = As + 16384;
        const size_t ko = (size_t)t * (BK * 2);
#pragma unroll
        for (int j = 0; j < 2; ++j)
            __builtin_amdgcn_global_load_lds(
                AS1(gS + (size_t)j * (64 * DIM * 2) + ko),
                AS3(As + (wid * 8 + j * 64) * 128), 16, 0, 0);
        __builtin_amdgcn_global_load_lds(
            AS1(gB + ko), AS3(Bs + wid * 8 * 128), 16, 0, 0);
    };

    // ---- prologue: two stages, then epi prefetch — ISSUE ORDER PINNED
    stage(0);
    __builtin_amdgcn_sched_barrier(0);
    stage(1);
    __builtin_amdgcn_sched_barrier(0);

    f32x4 eX[4], eE[4], eW[4], tv[4];
#pragma unroll
    for (int p = 0; p < 4; ++p) {
        const size_t v4 = evi(p);
        const int cv = (p * 512 + tid) & 15;
        eX[p] = ((const f32x4*)x)[v4];
        eE[p] = ((const f32x4*)ex)[v4];
        eW[p] = ((const f32x4*)W)[v4];
        tv[p] = ((const f32x4*)tgt)[bn * 16 + cv];
    }
    __builtin_amdgcn_sched_barrier(0);

    // ---- main loop: counted wait + raw barrier per step
    for (int t = 0; t < STEPS; ++t) {
        __builtin_amdgcn_sched_barrier(0);
        if (t == 0)             asm volatile("s_waitcnt vmcnt(19)" ::: "memory");
        else if (t == 1)        asm volatile("s_waitcnt vmcnt(20)" ::: "memory");
        else if (t <= 4)        asm volatile("s_waitcnt vmcnt(5)"  ::: "memory");
        else if (t == 5)        asm volatile("s_waitcnt vmcnt(4)"  ::: "memory");
        else if (t < STEPS - 1) asm volatile("s_waitcnt vmcnt(3)"  ::: "memory");
        else                    asm volatile("s_waitcnt vmcnt(0)"  ::: "memory");
        __builtin_amdgcn_sched_barrier(0);
        __builtin_amdgcn_s_barrier();
        __builtin_amdgcn_sched_barrier(0);
        if (t + 2 < STEPS) stage(t + 2);
        __builtin_amdgcn_sched_barrier(0);
        if (t < 4)   // out2 zeros ride the loop's idle write pipe
            ((f32x4*)out2)[evi(t)] = f32x4{0.f, 0.f, 0.f, 0.f};
        __builtin_amdgcn_sched_barrier(0);

        const char* As_ = lds + (t % 3) * BUF;
        const char* Bs_ = As_ + 16384;
#pragma unroll
        for (int kk = 0; kk < 2; ++kk) {
            bf16x8 af[2], bfr[2];
#pragma unroll
            for (int mi = 0; mi < 2; ++mi)
                af[mi] = *(const bf16x8*)(As_ + (wr * 32 + mi * 16 + l15) * 128 +
                                          ((cb0 + kk * 64) ^ rd_sw));
#pragma unroll
            for (int ni = 0; ni < 2; ++ni)
                bfr[ni] = *(const bf16x8*)(Bs_ + (wc * 32 + ni * 16 + l15) * 128 +
                                           ((cb0 + kk * 64) ^ rd_sw));
            __builtin_amdgcn_s_setprio(1);       // T5: favor MFMA-entering wave
#pragma unroll
            for (int mi = 0; mi < 2; ++mi)
#pragma unroll
                for (int ni = 0; ni < 2; ++ni)
                    acc[mi][ni] = __builtin_amdgcn_mfma_f32_16x16x32_bf16(
                        af[mi], bfr[ni], acc[mi][ni], 0, 0, 0);
            __builtin_amdgcn_s_setprio(0);
        }
    }

    // ---- epilogue: C -> LDS f32[128][64] (linear), then register epilogue
    __syncthreads();
#pragma unroll
    for (int mi = 0; mi < 2; ++mi)
#pragma unroll
        for (int ni = 0; ni < 2; ++ni) {
            const int row_ = wr * 32 + mi * 16 + ((lane >> 4) << 2);
            const int colb = (wc * 32 + ni * 16 + l15) * 4;
#pragma unroll
            for (int r = 0; r < 4; ++r)
                *(float*)(lds + (row_ + r) * 256 + colb) = acc[mi][ni][r];
        }
    __syncthreads();

#pragma unroll
    for (int p = 0; p < 4; ++p) {
        const int ci  = p * 512 + tid;           // 0..2047
        const int row = ci >> 4;                 // 0..127
        const int cv  = ci & 15;                 // 0..15
        f32x4 c = *(const f32x4*)(lds + row * 256 + cv * 16);
        const size_t v4 = (size_t)(bm * BM + row) * (DIM / 4) + bn * 16 + cv;
        f32x4 o0;
#pragma unroll
        for (int e = 0; e < 4; ++e) {
            float xi = eX[p][e], ti = tv[p][e];
            float ba = ti * ti * __builtin_amdgcn_rcpf(1.0f + ti * ti);
            float u  = -(eW[p][e] * (xi + eE[p][e] - ti)) * ba;
            float s  = sigma_f(xi);
            o0[e] = -xi + u * s + c[e];
        }
        ((f32x4*)out0)[v4] = o0;
        ((f32x4*)out1)[v4] = -o0;
    }
}

// ---------------------------------------------------------------------------
extern "C" void kernel_launch(void* const* d_in, const int* in_sizes, int n_in,
                              void* d_out, int out_size, void* d_ws, size_t ws_size,
                              hipStream_t stream)
{
    const float* x   = (const float*)d_in[0];
    const float* ex  = (const float*)d_in[1];
    const float* W   = (const float*)d_in[2];
    const float* A   = (const float*)d_in[3];
    const float* tgt = (const float*)d_in[4];

    float* out0 = (float*)d_out;
    float* out1 = out0 + (size_t)BATCH * DIM;
    float* out2 = out1 + (size_t)BATCH * DIM;

    unsigned short* sigb = (unsigned short*)d_ws;                                   // 16 MiB
    unsigned short* Abf  = (unsigned short*)((char*)d_ws + (size_t)16 * 1024 * 1024); // 2 MiB

    prep_kernel<<<4608, 256, 0, stream>>>(x, A, sigb, Abf);
    gemm_kernel<<<(BATCH / BM) * (DIM / BN), 512, 0, stream>>>(
        x, ex, W, tgt, sigb, Abf, out0, out1, out2);
}